// Round 4
// baseline (71.378 us; speedup 1.0000x reference)
//
#include <hip/hip_runtime.h>

#define B_ROWS   32768
#define D_DIM    512
#define NBLOCKS  2048            // main-pass grid: 8 blocks/CU -> 8 waves/SIMD
#define TPB      256             // 4 waves per block
#define NWAVES   (NBLOCKS * (TPB / 64))   // 8192
#define RPW      (B_ROWS / NWAVES)        // 4 rows per wave, exact

struct Ws {
    unsigned anchor_idx;   // min index with label==0
    int      cnt0;         // init -1; atomic += count  ->  ends at pos_cnt
};
// partials live at (float*)d_ws + 64 : [NBLOCKS][8] (pos[4], neg[4])

__device__ __forceinline__ float dot4(float4 a, float4 b) {
    return a.x * b.x + a.y * b.y + a.z * b.z + a.w * b.w;
}

// Reduce 8 independent per-lane values over all 64 lanes with 11 shuffles.
// On return, every lane in group g=(lane>>3) holds the full 64-lane total of
// value j=g  (j: 0..3 = dot[m], 4..7 = nrm[m]).
__device__ __forceinline__ float fold_reduce8(const float v[8], int lane) {
    float w[4];
    #pragma unroll
    for (int i = 0; i < 4; ++i) {
        float send = (lane & 32) ? v[i] : v[i + 4];
        float rcv  = __shfl_xor(send, 32);
        w[i] = ((lane & 32) ? v[i + 4] : v[i]) + rcv;
    }
    float u[2];
    #pragma unroll
    for (int i = 0; i < 2; ++i) {
        float send = (lane & 16) ? w[i] : w[i + 2];
        float rcv  = __shfl_xor(send, 16);
        u[i] = ((lane & 16) ? w[i + 2] : w[i]) + rcv;
    }
    float t;
    {
        float send = (lane & 8) ? u[0] : u[1];
        float rcv  = __shfl_xor(send, 8);
        t = ((lane & 8) ? u[1] : u[0]) + rcv;
    }
    t += __shfl_xor(t, 4);
    t += __shfl_xor(t, 2);
    t += __shfl_xor(t, 1);
    return t;
}

// ---------------------------------------------------------------- scan labels
__global__ void scan_labels_kernel(const int* __restrict__ label, Ws* ws) {
    int tid = blockIdx.x * blockDim.x + threadIdx.x;   // 32 blocks * 256
    const int4* L4 = (const int4*)label;
    int4 v = L4[tid];                                  // 8192 int4 = 32768 ints
    int cnt = (v.x == 0) + (v.y == 0) + (v.z == 0) + (v.w == 0);
    unsigned base = (unsigned)tid * 4;
    unsigned mymin = 0xFFFFFFFFu;
    if (v.w == 0) mymin = base + 3;
    if (v.z == 0) mymin = base + 2;
    if (v.y == 0) mymin = base + 1;
    if (v.x == 0) mymin = base;
    for (int off = 32; off; off >>= 1) {
        cnt += __shfl_xor(cnt, off);
        unsigned o = (unsigned)__shfl_xor((int)mymin, off);
        mymin = mymin < o ? mymin : o;
    }
    if ((threadIdx.x & 63) == 0) {
        if (cnt) atomicAdd(&ws->cnt0, cnt);
        if (mymin != 0xFFFFFFFFu) atomicMin(&ws->anchor_idx, mymin);
    }
}

// ---------------------------------------------------------------- main pass
// One wave per row (grid-stride). Anchor in LDS (keeps VGPR <= 64 so 8
// waves/SIMD stay resident). All 8 row-loads issued as one batch; 11-shuffle
// folded reduce. No global atomics.
__launch_bounds__(TPB)
__global__ void cos_accum_kernel(const int* __restrict__ label,
                                 const float* __restrict__ p_t,
                                 const float* __restrict__ p_a,
                                 const float* __restrict__ s_t,
                                 const float* __restrict__ s_a,
                                 const Ws* __restrict__ ws,
                                 float* __restrict__ partials) {
    const float* X[4] = {p_t, p_a, s_t, s_a};
    __shared__ float4 anc[4][D_DIM / 4];   // 8 KB
    __shared__ float  red[TPB / 64][8];

    const unsigned aidx = ws->anchor_idx;
    const int lane = threadIdx.x & 63;
    const int wid  = threadIdx.x >> 6;
    const int gwave = blockIdx.x * (TPB / 64) + wid;

    // stage anchor rows into LDS (once per block)
    for (int idx = threadIdx.x; idx < 4 * (D_DIM / 4); idx += TPB) {
        int m = idx >> 7;
        int j = idx & 127;
        anc[m][j] = ((const float4*)(X[m] + (size_t)aidx * D_DIM))[j];
    }
    __syncthreads();

    // per-wave anchor inverse-norms via one folded reduce:
    // lanes 0,8,16,24 end up holding 1/||a_m|| for m = lane>>3
    float inv_mine;
    {
        float va[8];
        #pragma unroll
        for (int m = 0; m < 4; ++m) {
            float4 a0 = anc[m][lane * 2];
            float4 a1 = anc[m][lane * 2 + 1];
            va[m]     = dot4(a0, a0) + dot4(a1, a1);
            va[m + 4] = 0.f;
        }
        inv_mine = rsqrtf(fold_reduce8(va, lane));
    }

    float posAcc = 0.f, negAcc = 0.f;

    #pragma unroll
    for (int k = 0; k < RPW; ++k) {
        unsigned r = (unsigned)gwave + (unsigned)k * NWAVES;
        int lab = label[r];

        // one batch of 8 dwordx4 loads (8 KB/wave in flight)
        float4 x[8];
        #pragma unroll
        for (int m = 0; m < 4; ++m) {
            const float4* Xr = (const float4*)(X[m] + (size_t)r * D_DIM) + lane * 2;
            x[2 * m]     = Xr[0];
            x[2 * m + 1] = Xr[1];
        }

        float v[8];
        #pragma unroll
        for (int m = 0; m < 4; ++m) {
            float4 b0 = anc[m][lane * 2];
            float4 b1 = anc[m][lane * 2 + 1];
            v[m]     = dot4(x[2 * m], b0)       + dot4(x[2 * m + 1], b1);
            v[m + 4] = dot4(x[2 * m], x[2 * m]) + dot4(x[2 * m + 1], x[2 * m + 1]);
        }
        float t     = fold_reduce8(v, lane);
        float other = __shfl_xor(t, 32);      // lane 8m (<32): t=dot_m, other=nrm_m
        if (((lane & 39) == 0) && (r != aidx)) {   // lanes 0,8,16,24
            float c = t * rsqrtf(other) * inv_mine;
            if (lab == 0) posAcc += c; else negAcc += c;
        }
    }

    if ((lane & 39) == 0) {
        int m = lane >> 3;
        red[wid][m]     = posAcc;
        red[wid][4 + m] = negAcc;
    }
    __syncthreads();
    if (threadIdx.x < 8) {
        int j = threadIdx.x;
        partials[blockIdx.x * 8 + j] = red[0][j] + red[1][j] + red[2][j] + red[3][j];
    }
}

// ---------------------------------------------------------------- finalize
__global__ void finalize_kernel(const Ws* __restrict__ ws,
                                const float* __restrict__ partials,
                                float* __restrict__ out) {
    __shared__ float red[256];
    int t = threadIdx.x;          // 256 threads
    int j = t & 7;
    float s = 0.f;
    for (int r = t >> 3; r < NBLOCKS; r += 32)
        s += partials[r * 8 + j];
    red[t] = s;
    __syncthreads();
    if (t < 8) {
        float tot = 0.f;
        #pragma unroll
        for (int k = 0; k < 32; ++k) tot += red[k * 8 + t];
        red[t] = tot;
    }
    __syncthreads();
    if (t == 0) {
        float pos_cnt = (float)ws->cnt0;              // count-1 (init was -1)
        float neg_cnt = (float)(B_ROWS - (ws->cnt0 + 1));
        float total = 0.f;
        #pragma unroll
        for (int m = 0; m < 4; ++m) {
            float ps = (pos_cnt > 0.f) ? red[m]     / fmaxf(pos_cnt, 1.f) : 0.f;
            float ns = (neg_cnt > 0.f) ? red[4 + m] / fmaxf(neg_cnt, 1.f) : 0.f;
            total += 2.0f - ps + ns;
        }
        out[0] = total * 0.25f;
    }
}

extern "C" void kernel_launch(void* const* d_in, const int* in_sizes, int n_in,
                              void* d_out, int out_size, void* d_ws, size_t ws_size,
                              hipStream_t stream) {
    const int*   label = (const int*)  d_in[0];
    const float* p_t   = (const float*)d_in[1];
    const float* p_a   = (const float*)d_in[2];
    const float* s_t   = (const float*)d_in[3];
    const float* s_a   = (const float*)d_in[4];
    Ws* ws = (Ws*)d_ws;
    float* partials = (float*)d_ws + 64;   // 256B past header

    // anchor_idx <- 0xFFFFFFFF ; cnt0 <- -1  (single 8-byte fill)
    hipMemsetAsync(d_ws, 0xFF, 8, stream);

    scan_labels_kernel <<<32,      TPB, 0, stream>>>(label, ws);
    cos_accum_kernel   <<<NBLOCKS, TPB, 0, stream>>>(label, p_t, p_a, s_t, s_a, ws, partials);
    finalize_kernel    <<<1,       TPB, 0, stream>>>(ws, partials, (float*)d_out);
}

// Round 5
// 71.340 us; speedup vs baseline: 1.0005x; 1.0005x over previous
//
#include <hip/hip_runtime.h>

#define B_ROWS   32768
#define D_DIM    512
#define NBLOCKS  2048            // 8 blocks/CU nominal
#define TPB      256             // 4 waves per block
#define NWAVES   (NBLOCKS * (TPB / 64))   // 8192
#define RPW      (B_ROWS / NWAVES)        // 4 rows per wave, exact

struct Ws {
    unsigned anchor_idx;   // min index with label==0
    int      cnt0;         // init -1; atomic += count  ->  ends at pos_cnt
};
// partials live at (float*)d_ws + 64 : [NBLOCKS][8] (pos[4], neg[4])

__device__ __forceinline__ float dot4(float4 a, float4 b) {
    return a.x * b.x + a.y * b.y + a.z * b.z + a.w * b.w;
}

// Reduce 8 independent per-lane values over all 64 lanes with 11 shuffles.
// On return, every lane in group g=(lane>>3) holds the full 64-lane total of
// value j=g  (j: 0..3 = dot[m], 4..7 = nrm[m]).
__device__ __forceinline__ float fold_reduce8(const float v[8], int lane) {
    float w[4];
    #pragma unroll
    for (int i = 0; i < 4; ++i) {
        float send = (lane & 32) ? v[i] : v[i + 4];
        float rcv  = __shfl_xor(send, 32);
        w[i] = ((lane & 32) ? v[i + 4] : v[i]) + rcv;
    }
    float u[2];
    #pragma unroll
    for (int i = 0; i < 2; ++i) {
        float send = (lane & 16) ? w[i] : w[i + 2];
        float rcv  = __shfl_xor(send, 16);
        u[i] = ((lane & 16) ? w[i + 2] : w[i]) + rcv;
    }
    float t;
    {
        float send = (lane & 8) ? u[0] : u[1];
        float rcv  = __shfl_xor(send, 8);
        t = ((lane & 8) ? u[1] : u[0]) + rcv;
    }
    t += __shfl_xor(t, 4);
    t += __shfl_xor(t, 2);
    t += __shfl_xor(t, 1);
    return t;
}

// ---------------------------------------------------------------- scan labels
__global__ void scan_labels_kernel(const int* __restrict__ label, Ws* ws) {
    int tid = blockIdx.x * blockDim.x + threadIdx.x;   // 32 blocks * 256
    const int4* L4 = (const int4*)label;
    int4 v = L4[tid];                                  // 8192 int4 = 32768 ints
    int cnt = (v.x == 0) + (v.y == 0) + (v.z == 0) + (v.w == 0);
    unsigned base = (unsigned)tid * 4;
    unsigned mymin = 0xFFFFFFFFu;
    if (v.w == 0) mymin = base + 3;
    if (v.z == 0) mymin = base + 2;
    if (v.y == 0) mymin = base + 1;
    if (v.x == 0) mymin = base;
    for (int off = 32; off; off >>= 1) {
        cnt += __shfl_xor(cnt, off);
        unsigned o = (unsigned)__shfl_xor((int)mymin, off);
        mymin = mymin < o ? mymin : o;
    }
    if ((threadIdx.x & 63) == 0) {
        if (cnt) atomicAdd(&ws->cnt0, cnt);
        if (mymin != 0xFFFFFFFFu) atomicMin(&ws->anchor_idx, mymin);
    }
}

// ---------------------------------------------------------------- main pass
// One wave per row (grid-stride). DENSE access: load instruction c of a row
// covers contiguous bytes [c*1024, c*1024+1024) with lane offset lane*16 --
// every dwordx4 is 8 fully-used cache lines; LDS reads are the canonical
// conflict-free stride-16B ds_read_b128 pattern. launch_bounds(,6) gives the
// register allocator room (cap 85 VGPR) to keep all 8 row-loads in flight.
__launch_bounds__(TPB, 6)
__global__ void cos_accum_kernel(const int* __restrict__ label,
                                 const float* __restrict__ p_t,
                                 const float* __restrict__ p_a,
                                 const float* __restrict__ s_t,
                                 const float* __restrict__ s_a,
                                 const Ws* __restrict__ ws,
                                 float* __restrict__ partials) {
    const float* X[4] = {p_t, p_a, s_t, s_a};
    __shared__ float4 anc4[4 * 128];       // 8 KB, [m*128 + c*64 + lane]
    __shared__ float  red[TPB / 64][8];

    const unsigned aidx = ws->anchor_idx;
    const int lane = threadIdx.x & 63;
    const int wid  = threadIdx.x >> 6;
    const int gwave = blockIdx.x * (TPB / 64) + wid;

    // stage anchor rows into LDS (dense copy, once per block)
    for (int idx = threadIdx.x; idx < 4 * 128; idx += TPB) {
        anc4[idx] = ((const float4*)(X[idx >> 7] + (size_t)aidx * D_DIM))[idx & 127];
    }
    __syncthreads();

    // per-wave anchor inverse-norms via one folded reduce:
    // lanes 0,8,16,24 end up holding 1/||a_m|| for m = lane>>3
    float inv_mine;
    {
        float va[8];
        #pragma unroll
        for (int m = 0; m < 4; ++m) {
            float4 a0 = anc4[(m << 7) + lane];
            float4 a1 = anc4[(m << 7) + 64 + lane];
            va[m]     = dot4(a0, a0) + dot4(a1, a1);
            va[m + 4] = 0.f;
        }
        inv_mine = rsqrtf(fold_reduce8(va, lane));
    }

    float posAcc = 0.f, negAcc = 0.f;

    #pragma unroll
    for (int k = 0; k < RPW; ++k) {
        unsigned r = (unsigned)gwave + (unsigned)k * NWAVES;
        // wave-uniform scalar load keeps the VMEM path clear
        int lab = label[__builtin_amdgcn_readfirstlane((int)r)];

        // one batch of 8 dwordx4 loads, each a dense 1KB wave access
        float4 x[8];
        #pragma unroll
        for (int m = 0; m < 4; ++m) {
            const float4* Xr = (const float4*)(X[m]) + (size_t)r * (D_DIM / 4);
            x[2 * m]     = Xr[lane];
            x[2 * m + 1] = Xr[64 + lane];
        }

        float v[8];
        #pragma unroll
        for (int m = 0; m < 4; ++m) {
            float4 b0 = anc4[(m << 7) + lane];
            float4 b1 = anc4[(m << 7) + 64 + lane];
            v[m]     = dot4(x[2 * m], b0)       + dot4(x[2 * m + 1], b1);
            v[m + 4] = dot4(x[2 * m], x[2 * m]) + dot4(x[2 * m + 1], x[2 * m + 1]);
        }
        float t     = fold_reduce8(v, lane);
        float other = __shfl_xor(t, 32);      // lane 8m (<32): t=dot_m, other=nrm_m
        if (((lane & 39) == 0) && (r != aidx)) {   // lanes 0,8,16,24
            float c = t * rsqrtf(other) * inv_mine;
            if (lab == 0) posAcc += c; else negAcc += c;
        }
    }

    if ((lane & 39) == 0) {
        int m = lane >> 3;
        red[wid][m]     = posAcc;
        red[wid][4 + m] = negAcc;
    }
    __syncthreads();
    if (threadIdx.x < 8) {
        int j = threadIdx.x;
        partials[blockIdx.x * 8 + j] = red[0][j] + red[1][j] + red[2][j] + red[3][j];
    }
}

// ---------------------------------------------------------------- finalize
__global__ void finalize_kernel(const Ws* __restrict__ ws,
                                const float* __restrict__ partials,
                                float* __restrict__ out) {
    __shared__ float red[256];
    int t = threadIdx.x;          // 256 threads
    int j = t & 7;
    float s = 0.f;
    for (int r = t >> 3; r < NBLOCKS; r += 32)
        s += partials[r * 8 + j];
    red[t] = s;
    __syncthreads();
    if (t < 8) {
        float tot = 0.f;
        #pragma unroll
        for (int k = 0; k < 32; ++k) tot += red[k * 8 + t];
        red[t] = tot;
    }
    __syncthreads();
    if (t == 0) {
        float pos_cnt = (float)ws->cnt0;              // count-1 (init was -1)
        float neg_cnt = (float)(B_ROWS - (ws->cnt0 + 1));
        float total = 0.f;
        #pragma unroll
        for (int m = 0; m < 4; ++m) {
            float ps = (pos_cnt > 0.f) ? red[m]     / fmaxf(pos_cnt, 1.f) : 0.f;
            float ns = (neg_cnt > 0.f) ? red[4 + m] / fmaxf(neg_cnt, 1.f) : 0.f;
            total += 2.0f - ps + ns;
        }
        out[0] = total * 0.25f;
    }
}

extern "C" void kernel_launch(void* const* d_in, const int* in_sizes, int n_in,
                              void* d_out, int out_size, void* d_ws, size_t ws_size,
                              hipStream_t stream) {
    const int*   label = (const int*)  d_in[0];
    const float* p_t   = (const float*)d_in[1];
    const float* p_a   = (const float*)d_in[2];
    const float* s_t   = (const float*)d_in[3];
    const float* s_a   = (const float*)d_in[4];
    Ws* ws = (Ws*)d_ws;
    float* partials = (float*)d_ws + 64;   // 256B past header

    // anchor_idx <- 0xFFFFFFFF ; cnt0 <- -1  (single 8-byte fill)
    hipMemsetAsync(d_ws, 0xFF, 8, stream);

    scan_labels_kernel <<<32,      TPB, 0, stream>>>(label, ws);
    cos_accum_kernel   <<<NBLOCKS, TPB, 0, stream>>>(label, p_t, p_a, s_t, s_a, ws, partials);
    finalize_kernel    <<<1,       TPB, 0, stream>>>(ws, partials, (float*)d_out);
}

// Round 6
// 61.257 us; speedup vs baseline: 1.1652x; 1.1646x over previous
//
#include <hip/hip_runtime.h>
#include <cstdint>

#define B_ROWS   32768
#define D_DIM    512
#define NBLOCKS  512             // 2 blocks/CU exactly (LDS-capped), all resident
#define TPB      256             // 4 waves per block
#define WPB      (TPB / 64)
#define NWAVES   (NBLOCKS * WPB)          // 2048
#define RPW      (B_ROWS / NWAVES)        // 16 rows per wave, exact

struct Ws {
    unsigned anchor_idx;   // min index with label==0
    int      cnt0;         // init -1; atomic += count  ->  ends at pos_cnt
};
// partials live at (float*)d_ws + 64 : [NBLOCKS][8] (pos[4], neg[4])

// Hand-placed waitcnt + mandatory scheduling fence (guide rule #18).
#define WAITVM(N) do { asm volatile("s_waitcnt vmcnt(" #N ")" ::: "memory"); \
                       __builtin_amdgcn_sched_barrier(0); } while (0)

typedef __attribute__((address_space(3))) unsigned int lds_u32;
typedef const __attribute__((address_space(1))) unsigned int glb_u32;

// One call stages 1 KB: HW writes each lane's 16B at (dst + lane*16).
// src is PER-LANE (must already include lane*16); dst is wave-uniform.
// CK-style integer round-trip: low 32 bits of a generic LDS address are the
// LDS byte offset; global generic == AS1 on gfx9+.
__device__ __forceinline__ void dma1k(const float* src, const float4* dst) {
    __builtin_amdgcn_global_load_lds((glb_u32*)(uintptr_t)src,
                                     (lds_u32*)(unsigned int)(uintptr_t)dst,
                                     16, 0, 0);
}

// Stage one full row (4 modalities x 2KB) = 8 DMA ops = vmcnt +8.
__device__ __forceinline__ void dma_row(const float* const X[4], unsigned r,
                                        const float4* dstbase, int lane) {
    #pragma unroll
    for (int m = 0; m < 4; ++m) {
        const float* src = X[m] + (size_t)r * D_DIM + lane * 4;
        dma1k(src,       dstbase + m * 128);
        dma1k(src + 256, dstbase + m * 128 + 64);
    }
}

__device__ __forceinline__ float dot4(float4 a, float4 b) {
    return a.x * b.x + a.y * b.y + a.z * b.z + a.w * b.w;
}

// Reduce 8 independent per-lane values over 64 lanes with 11 shuffles.
// Lane group g=(lane>>3) ends holding the total of value j=g.
__device__ __forceinline__ float fold_reduce8(const float v[8], int lane) {
    float w[4];
    #pragma unroll
    for (int i = 0; i < 4; ++i) {
        float send = (lane & 32) ? v[i] : v[i + 4];
        float rcv  = __shfl_xor(send, 32);
        w[i] = ((lane & 32) ? v[i + 4] : v[i]) + rcv;
    }
    float u[2];
    #pragma unroll
    for (int i = 0; i < 2; ++i) {
        float send = (lane & 16) ? w[i] : w[i + 2];
        float rcv  = __shfl_xor(send, 16);
        u[i] = ((lane & 16) ? w[i + 2] : w[i]) + rcv;
    }
    float t;
    {
        float send = (lane & 8) ? u[0] : u[1];
        float rcv  = __shfl_xor(send, 8);
        t = ((lane & 8) ? u[1] : u[0]) + rcv;
    }
    t += __shfl_xor(t, 4);
    t += __shfl_xor(t, 2);
    t += __shfl_xor(t, 1);
    return t;
}

// ---------------------------------------------------------------- scan labels
__global__ void scan_labels_kernel(const int* __restrict__ label, Ws* ws) {
    int tid = blockIdx.x * blockDim.x + threadIdx.x;   // 32 blocks * 256
    const int4* L4 = (const int4*)label;
    int4 v = L4[tid];
    int cnt = (v.x == 0) + (v.y == 0) + (v.z == 0) + (v.w == 0);
    unsigned base = (unsigned)tid * 4;
    unsigned mymin = 0xFFFFFFFFu;
    if (v.w == 0) mymin = base + 3;
    if (v.z == 0) mymin = base + 2;
    if (v.y == 0) mymin = base + 1;
    if (v.x == 0) mymin = base;
    for (int off = 32; off; off >>= 1) {
        cnt += __shfl_xor(cnt, off);
        unsigned o = (unsigned)__shfl_xor((int)mymin, off);
        mymin = mymin < o ? mymin : o;
    }
    if ((threadIdx.x & 63) == 0) {
        if (cnt) atomicAdd(&ws->cnt0, cnt);
        if (mymin != 0xFFFFFFFFu) atomicMin(&ws->anchor_idx, mymin);
    }
}

// ---------------------------------------------------------------- main pass
// Per-wave DMA streaming: global_load_lds double-buffer, 2 rows (16 KB) in
// flight per wave at all times, zero destination VGPRs, hand-placed vmcnt.
__launch_bounds__(TPB, 2)
__global__ void cos_accum_kernel(const int* __restrict__ label,
                                 const float* __restrict__ p_t,
                                 const float* __restrict__ p_a,
                                 const float* __restrict__ s_t,
                                 const float* __restrict__ s_a,
                                 const Ws* __restrict__ ws,
                                 float* __restrict__ partials) {
    const float* X[4] = {p_t, p_a, s_t, s_a};
    __shared__ float4 buf[WPB][2][512];   // 4 waves x 2 bufs x 8 KB = 64 KB
    __shared__ float  red[WPB][8];

    const unsigned aidx = ws->anchor_idx;
    const int lane = threadIdx.x & 63;
    const int wid  = __builtin_amdgcn_readfirstlane((int)(threadIdx.x >> 6));
    const unsigned gwave = (unsigned)blockIdx.x * WPB + (unsigned)wid;

    // ---- prologue: anchor reg-loads FIRST (oldest vmcnt slots) ----
    float4 an[8];
    #pragma unroll
    for (int m = 0; m < 4; ++m) {
        const float4* A = (const float4*)(X[m] + (size_t)aidx * D_DIM);
        an[2 * m]     = A[lane];
        an[2 * m + 1] = A[64 + lane];
    }
    // then the first two row-DMAs (16 ops outstanding)
    dma_row(X, gwave,          &buf[wid][0][0], lane);
    dma_row(X, gwave + NWAVES, &buf[wid][1][0], lane);

    // labels: wave-uniform scalar loads (lgkm path, no vmcnt pollution)
    int lab[RPW];
    #pragma unroll
    for (int k = 0; k < RPW; ++k) lab[k] = label[gwave + (unsigned)k * NWAVES];

    // anchor inverse-norms: lanes 0,8,16,24 hold 1/||a_m|| for m=lane>>3
    float inv_mine;
    {
        float va[8];
        #pragma unroll
        for (int m = 0; m < 4; ++m) {
            va[m]     = dot4(an[2 * m], an[2 * m]) + dot4(an[2 * m + 1], an[2 * m + 1]);
            va[m + 4] = 0.f;
        }
        inv_mine = rsqrtf(fold_reduce8(va, lane));
    }

    float posAcc = 0.f, negAcc = 0.f;

    #pragma unroll
    for (int k = 0; k < RPW; ++k) {
        if (k < RPW - 1) { WAITVM(8); }   // row k landed; row k+1 still in flight
        else            { WAITVM(0); }    // final row

        const unsigned r = gwave + (unsigned)k * NWAVES;
        const float4* bp = &buf[wid][k & 1][0];

        float4 x[8];
        #pragma unroll
        for (int m = 0; m < 4; ++m) {
            x[2 * m]     = bp[m * 128 + lane];
            x[2 * m + 1] = bp[m * 128 + 64 + lane];
        }
        float v[8];
        #pragma unroll
        for (int m = 0; m < 4; ++m) {
            v[m]     = dot4(x[2 * m], an[2 * m]) + dot4(x[2 * m + 1], an[2 * m + 1]);
            v[m + 4] = dot4(x[2 * m], x[2 * m])  + dot4(x[2 * m + 1], x[2 * m + 1]);
        }

        // buffer k&1 fully consumed into v[] -> safe to re-issue DMA into it.
        // DMA's LDS write lands >=~300cy after issue, far after these ds_reads.
        if (k + 2 < RPW)
            dma_row(X, gwave + (unsigned)(k + 2) * NWAVES, &buf[wid][k & 1][0], lane);

        float t     = fold_reduce8(v, lane);
        float other = __shfl_xor(t, 32);       // lane 8m (<32): t=dot_m, other=nrm_m
        if (((lane & 39) == 0) && (r != aidx)) {   // lanes 0,8,16,24
            float c = t * rsqrtf(other) * inv_mine;
            if (lab[k] == 0) posAcc += c; else negAcc += c;
        }
    }

    if ((lane & 39) == 0) {
        int m = lane >> 3;
        red[wid][m]     = posAcc;
        red[wid][4 + m] = negAcc;
    }
    __syncthreads();
    if (threadIdx.x < 8) {
        int j = threadIdx.x;
        partials[blockIdx.x * 8 + j] = red[0][j] + red[1][j] + red[2][j] + red[3][j];
    }
}

// ---------------------------------------------------------------- finalize
__global__ void finalize_kernel(const Ws* __restrict__ ws,
                                const float* __restrict__ partials,
                                float* __restrict__ out) {
    __shared__ float red[256];
    int t = threadIdx.x;          // 256 threads
    int j = t & 7;
    float s = 0.f;
    for (int r = t >> 3; r < NBLOCKS; r += 32)
        s += partials[r * 8 + j];
    red[t] = s;
    __syncthreads();
    if (t < 8) {
        float tot = 0.f;
        #pragma unroll
        for (int k = 0; k < 32; ++k) tot += red[k * 8 + t];
        red[t] = tot;
    }
    __syncthreads();
    if (t == 0) {
        float pos_cnt = (float)ws->cnt0;              // count-1 (init was -1)
        float neg_cnt = (float)(B_ROWS - (ws->cnt0 + 1));
        float total = 0.f;
        #pragma unroll
        for (int m = 0; m < 4; ++m) {
            float ps = (pos_cnt > 0.f) ? red[m]     / fmaxf(pos_cnt, 1.f) : 0.f;
            float ns = (neg_cnt > 0.f) ? red[4 + m] / fmaxf(neg_cnt, 1.f) : 0.f;
            total += 2.0f - ps + ns;
        }
        out[0] = total * 0.25f;
    }
}

extern "C" void kernel_launch(void* const* d_in, const int* in_sizes, int n_in,
                              void* d_out, int out_size, void* d_ws, size_t ws_size,
                              hipStream_t stream) {
    const int*   label = (const int*)  d_in[0];
    const float* p_t   = (const float*)d_in[1];
    const float* p_a   = (const float*)d_in[2];
    const float* s_t   = (const float*)d_in[3];
    const float* s_a   = (const float*)d_in[4];
    Ws* ws = (Ws*)d_ws;
    float* partials = (float*)d_ws + 64;   // 256B past header

    // anchor_idx <- 0xFFFFFFFF ; cnt0 <- -1  (single 8-byte fill)
    hipMemsetAsync(d_ws, 0xFF, 8, stream);

    scan_labels_kernel <<<32,      TPB, 0, stream>>>(label, ws);
    cos_accum_kernel   <<<NBLOCKS, TPB, 0, stream>>>(label, p_t, p_a, s_t, s_a, ws, partials);
    finalize_kernel    <<<1,       TPB, 0, stream>>>(ws, partials, (float*)d_out);
}